// Round 5
// baseline (1440.450 us; speedup 1.0000x reference)
//
#include <hip/hip_runtime.h>
#include <hip/hip_bf16.h>

#define NROWS 131072   // B*H*W = 32*64*64
#define DDIM  64
#define KCODES 1024
#define HW    4096     // H*W

// d_out is FLOAT32. Element offsets (reference return order):
#define OFF_ZQ   0ull        // 8388608  [B,C,H,W]
#define OFF_IDX  8388608ull  // 131072
#define OFF_LOSS 8519680ull  // 1
#define OFF_EMB  8519681ull  // 65536
#define OFF_NCS  8585217ull  // 1024
#define OFF_EAVG 8586241ull  // 65536  (end 8651777)

// Scratch INSIDE d_out on top of emb/ncs/eavg f32 regions (finalize rewrites):
#define SCR_B0     34078724ull   // = 4*OFF_EMB
#define SCR_ZERO_N 266244ull

// Fast-scan top-2 gap below this => wave-cooperative np-exact rescan.
// Bound on |np_dist - (x2 + fast_val)| is ~1.6e-5; 1e-4 gives 6x safety.
#define RESCAN_GAP 1e-4f

// numpy pairwise_sum (n=64 base case): 8 accumulators over pre-rounded
// products, combine tree ((r0+r1)+(r2+r3))+((r4+r5)+(r6+r7)).
__device__ __forceinline__ float np_sumsq64(const float* v) {
#pragma clang fp contract(off)
    float r0 = v[0] * v[0], r1 = v[1] * v[1], r2 = v[2] * v[2], r3 = v[3] * v[3];
    float r4 = v[4] * v[4], r5 = v[5] * v[5], r6 = v[6] * v[6], r7 = v[7] * v[7];
    for (int i = 8; i < 64; i += 8) {
        r0 += v[i + 0] * v[i + 0];
        r1 += v[i + 1] * v[i + 1];
        r2 += v[i + 2] * v[i + 2];
        r3 += v[i + 3] * v[i + 3];
        r4 += v[i + 4] * v[i + 4];
        r5 += v[i + 5] * v[i + 5];
        r6 += v[i + 6] * v[i + 6];
        r7 += v[i + 7] * v[i + 7];
    }
    return ((r0 + r1) + (r2 + r3)) + ((r4 + r5) + (r6 + r7));
}

__global__ __launch_bounds__(256) void assign_kernel(
        const float* __restrict__ z, const float* __restrict__ emb,
        float* __restrict__ out,
        float* __restrict__ esum, unsigned int* __restrict__ cnt,
        float* __restrict__ lossAcc) {
    __shared__ float w2np[KCODES];   // np-exact ||w_k||^2 (pairwise-8)
    const int tid = threadIdx.x;

    for (int r = 0; r < 4; ++r) {
        const int c = tid + 256 * r;
        w2np[c] = np_sumsq64(emb + c * DDIM);
    }
    __syncthreads();

    const int n = blockIdx.x * 256 + tid;
    const int w = n & 63, h = (n >> 6) & 63, b = n >> 12;
    const float* zb = z + (size_t)b * DDIM * HW + h * 64 + w;
    float x[DDIM];
#pragma unroll
    for (int d = 0; d < DDIM; ++d) x[d] = zb[(size_t)d * HW];

    const float x2np = np_sumsq64(x);   // np-exact row ||x||^2

    // fast pass (any rounding): top-2 of  w2_k - 2 x.w_k
    float min1 = 1e30f, min2 = 1e30f;
    int k1 = 0;
    for (int k = 0; k < KCODES; ++k) {
        const float* wk = emb + k * DDIM;   // wave-uniform address
        float a0 = 0.f, a1 = 0.f, a2 = 0.f, a3 = 0.f;
#pragma unroll
        for (int d = 0; d < DDIM; d += 4) {
            a0 = fmaf(x[d],     wk[d],     a0);
            a1 = fmaf(x[d + 1], wk[d + 1], a1);
            a2 = fmaf(x[d + 2], wk[d + 2], a2);
            a3 = fmaf(x[d + 3], wk[d + 3], a3);
        }
        const float val = fmaf(-2.f, (a0 + a1) + (a2 + a3), w2np[k]);
        const bool c1 = val < min1;
        min2 = c1 ? min1 : (val < min2 ? val : min2);
        min1 = c1 ? val : min1;
        k1   = c1 ? k : k1;
    }

    // flagged rows: full np-exact f32 rescan (wave-cooperative).
    // dist_k = RN( RN(x2 + w2_k) - 2 * seqfma_dot(x, w_k) ), first-index min.
    const int lane = tid & 63;
    unsigned long long need = __ballot((min2 - min1) < RESCAN_GAP);
    while (need) {
        const int src = __ffsll(need) - 1;
        need &= need - 1;
        const float x2s = __shfl(x2np, src, 64);
        float acc[16];
#pragma unroll
        for (int j = 0; j < 16; ++j) acc[j] = 0.f;
        for (int d = 0; d < DDIM; ++d) {
            const float xd = __shfl(x[d], src, 64);
#pragma unroll
            for (int j = 0; j < 16; ++j)
                acc[j] = fmaf(emb[(size_t)(lane + 64 * j) * DDIM + d], xd, acc[j]);
        }
        float bv = 1e30f;
        int bk = KCODES;
#pragma unroll
        for (int j = 0; j < 16; ++j) {
            const int kk = lane + 64 * j;
            float s, dv;
            {
#pragma clang fp contract(off)
                s  = x2s + w2np[kk];
                dv = s - 2.0f * acc[j];   // 2*acc exact -> rounding == np
            }
            if (dv < bv) { bv = dv; bk = kk; }
        }
        for (int off = 32; off > 0; off >>= 1) {
            const float ov = __shfl_xor(bv, off, 64);
            const int   ok = __shfl_xor(bk, off, 64);
            if (ov < bv || (ov == bv && ok < bk)) { bv = ov; bk = ok; }
        }
        if (lane == src) k1 = bk;
    }

    out[OFF_IDX + (size_t)(unsigned)n] = (float)k1;

    // z_q gather + f32 write (NCHW, coalesced) + loss partial
    const float* wk1 = emb + k1 * DDIM;
    float* ozb = out + (size_t)b * DDIM * HW + h * 64 + w;
    float ls = 0.f;
#pragma unroll
    for (int d = 0; d < DDIM; ++d) {
        const float wv = wk1[d];
        ozb[(size_t)d * HW] = wv;
        const float diff = x[d] - wv;
        ls = fmaf(diff, diff, ls);
    }

    // EMA accumulators (scratch inside d_out tail)
    atomicAdd(&cnt[k1], 1u);
#pragma unroll 8
    for (int d = 0; d < DDIM; ++d)
        atomicAdd(&esum[(size_t)k1 * DDIM + d], x[d]);

    // loss: wave shuffle -> LDS -> one atomic per block
#pragma unroll
    for (int off = 32; off > 0; off >>= 1) ls += __shfl_down(ls, off, 64);
    __shared__ float red[4];
    if (lane == 0) red[tid >> 6] = ls;
    __syncthreads();
    if (tid == 0)
        atomicAdd(lossAcc, red[0] + red[1] + red[2] + red[3]);
}

__global__ __launch_bounds__(1024) void finalize_kernel(
        const float* __restrict__ cs, const float* __restrict__ eavg,
        float* __restrict__ out,
        const float* __restrict__ esum, const unsigned int* __restrict__ cnt,
        const float* __restrict__ lossAcc) {
    const int k = threadIdx.x;

    float es[DDIM];
#pragma unroll
    for (int d = 0; d < DDIM; ++d) es[d] = esum[(size_t)k * DDIM + d];
    const float cntk = (float)cnt[k];
    const float lossv = lossAcc[0];
    const float ncs = fmaf(0.01f, cntk, 0.99f * cs[k]);

    __shared__ float red[1024];
    red[k] = ncs;
    __syncthreads();
    for (int s = 512; s > 0; s >>= 1) {
        if (k < s) red[k] += red[k + s];
        __syncthreads();
    }
    const float nn = red[0];
    const float smoothed = (ncs + 1e-5f) / (nn + 1024.f * 1e-5f) * nn;

    out[OFF_NCS + (size_t)k] = ncs;
#pragma unroll
    for (int d = 0; d < DDIM; ++d) {
        const float ea = fmaf(0.01f, es[d], 0.99f * eavg[(size_t)k * DDIM + d]);
        out[OFF_EAVG + (size_t)k * DDIM + d] = ea;
        out[OFF_EMB  + (size_t)k * DDIM + d] = ea / smoothed;
    }
    if (k == 0)
        out[OFF_LOSS] = 0.25f * lossv / 8388608.f;
}

extern "C" void kernel_launch(void* const* d_in, const int* in_sizes, int n_in,
                              void* d_out, int out_size, void* d_ws, size_t ws_size,
                              hipStream_t stream) {
    const float* z    = (const float*)d_in[0];
    const float* emb  = (const float*)d_in[1];
    const float* cs   = (const float*)d_in[2];
    const float* eavg = (const float*)d_in[3];
    float* out = (float*)d_out;

    float*        esum  = (float*)((char*)d_out + SCR_B0);
    unsigned int* cnt   = (unsigned int*)((char*)d_out + SCR_B0 + 262144);
    float*        lossA = (float*)((char*)d_out + SCR_B0 + 266240);

    hipMemsetAsync((char*)d_out + SCR_B0, 0, SCR_ZERO_N, stream);

    assign_kernel<<<NROWS / 256, 256, 0, stream>>>(z, emb, out, esum, cnt, lossA);
    finalize_kernel<<<1, 1024, 0, stream>>>(cs, eavg, out, esum, cnt, lossA);
}

// Round 7
// 619.888 us; speedup vs baseline: 2.3237x; 2.3237x over previous
//
#include <hip/hip_runtime.h>
#include <hip/hip_bf16.h>

#define NROWS 131072   // B*H*W
#define DDIM  64
#define KCODES 1024
#define HW    4096

// d_out is FLOAT32. Element offsets (reference return order):
#define OFF_ZQ   0ull
#define OFF_IDX  8388608ull
#define OFF_LOSS 8519680ull
#define OFF_EMB  8519681ull
#define OFF_NCS  8585217ull
#define OFF_EAVG 8586241ull   // end 8651777

// Scratch INSIDE d_out over the emb/ncs/eavg f32 regions (528,384 B),
// fully consumed-then-rewritten by finalize. Exact fit:
//   esum f32[65536] @ +0        (262144 B)
//   cnt  u32[1024]  @ +262144   (4096 B)
//   wh  bf16[65536] @ +266240   (131072 B)
//   wl  bf16[65536] @ +397312   (131072 B)
#define SCR_B0   34078724ull
#define SCR_CNT  (SCR_B0 + 262144ull)
#define SCR_WH   (SCR_B0 + 266240ull)
#define SCR_WL   (SCR_B0 + 397312ull)

#define GAPTHR 6e-5f

typedef __attribute__((ext_vector_type(8))) short bf16x8;
typedef __attribute__((ext_vector_type(4))) float f32x4;

// numpy pairwise base-case (n=64): 8 accumulators over pre-rounded products.
__device__ __forceinline__ float np_sumsq64(const float* v) {
#pragma clang fp contract(off)
    float r0 = v[0]*v[0], r1 = v[1]*v[1], r2 = v[2]*v[2], r3 = v[3]*v[3];
    float r4 = v[4]*v[4], r5 = v[5]*v[5], r6 = v[6]*v[6], r7 = v[7]*v[7];
    for (int i = 8; i < 64; i += 8) {
        r0 += v[i+0]*v[i+0]; r1 += v[i+1]*v[i+1];
        r2 += v[i+2]*v[i+2]; r3 += v[i+3]*v[i+3];
        r4 += v[i+4]*v[i+4]; r5 += v[i+5]*v[i+5];
        r6 += v[i+6]*v[i+6]; r7 += v[i+7]*v[i+7];
    }
    return ((r0+r1)+(r2+r3))+((r4+r5)+(r6+r7));
}

// contraction-proof helpers for np-exact rounding emulation
__device__ __forceinline__ float mul_rn(float a, float b) {
#pragma clang fp contract(off)
    return a * b;
}
__device__ __forceinline__ float add_rn(float a, float b) {
#pragma clang fp contract(off)
    return a + b;
}
__device__ __forceinline__ float sub2_rn(float s, float a) {
#pragma clang fp contract(off)
    return s - 2.0f * a;   // 2*a is exact; single rounding on the subtract
}

__device__ __forceinline__ unsigned bf16rne(float v) {
    unsigned b = __float_as_uint(v);
    return (b + 0x7FFFu + ((b >> 16) & 1u)) >> 16;
}
__device__ __forceinline__ float bfu2f(unsigned short u) {
    return __uint_as_float(((unsigned)u) << 16);
}
__device__ __forceinline__ unsigned flipf(float v) {
    unsigned b = __float_as_uint(v);
    return b ^ (0x80000000u | (unsigned)((int)b >> 31));
}
__device__ __forceinline__ float unflip_val(unsigned u) {
    u &= 0xFFFFFC00u;
    unsigned mask = 0x80000000u | (unsigned)((int)(~u) >> 31);
    return __uint_as_float(u ^ mask);
}

__global__ __launch_bounds__(256) void prep_kernel(
        const float* __restrict__ emb, float* __restrict__ out,
        unsigned short* __restrict__ wh, unsigned short* __restrict__ wl) {
    const int k = blockIdx.x * 256 + threadIdx.x;
    const float* w = emb + k * DDIM;
    for (int d = 0; d < DDIM; ++d) {
        const float v = w[d];
        const unsigned rh = bf16rne(v);
        const float lv = v - bfu2f((unsigned short)rh);
        wh[k * DDIM + d] = (unsigned short)rh;
        wl[k * DDIM + d] = (unsigned short)bf16rne(lv);
    }
    if (k == 0) out[OFF_LOSS] = 0.f;   // loss accumulator
}

__global__ __launch_bounds__(256, 2) void assign_kernel(
        const float* __restrict__ z, const float* __restrict__ emb,
        float* __restrict__ out,
        const unsigned short* __restrict__ wh, const unsigned short* __restrict__ wl,
        float* __restrict__ esum, unsigned int* __restrict__ cnt,
        float* __restrict__ lossAcc) {
    __shared__ unsigned short sxh[256][72];   // row-major x-hi, pad 72
    __shared__ unsigned short sxl[256][72];
    __shared__ float w2s[KCODES];
    __shared__ unsigned k1s[256];

    const int tid = threadIdx.x;
    const int lane = tid & 63, wid = tid >> 6;
    const int col = lane & 15, grp = lane >> 4;

    // np-exact ||w||^2 (same as verified round-5 path)
    for (int r = 0; r < 4; ++r) {
        const int c = tid + 256 * r;
        w2s[c] = np_sumsq64(emb + c * DDIM);
    }

    // stage this thread's row into LDS as bf16 hi/lo
    const int n0 = blockIdx.x * 256 + tid;
    const int w0 = n0 & 63, h0 = (n0 >> 6) & 63, b0 = n0 >> 12;
    {
        const float* zb = z + (size_t)b0 * DDIM * HW + h0 * 64 + w0;
        for (int d = 0; d < DDIM; ++d) {
            const float v = zb[(size_t)d * HW];
            const unsigned rh = bf16rne(v);
            const float lv = v - bfu2f((unsigned short)rh);
            sxh[tid][d] = (unsigned short)rh;
            sxl[tid][d] = (unsigned short)bf16rne(lv);
        }
    }
    __syncthreads();

    // hoist B-frags (x side): 4 row-tiles x 2 k-halves, hi & lo
    bf16x8 fxh[4][2], fxl[4][2];
#pragma unroll
    for (int rt = 0; rt < 4; ++rt) {
        const int row = wid * 64 + rt * 16 + col;
#pragma unroll
        for (int kh = 0; kh < 2; ++kh) {
            const int koff = grp * 8 + kh * 32;
            fxh[rt][kh] = *(const bf16x8*)&sxh[row][koff];
            fxl[rt][kh] = *(const bf16x8*)&sxl[row][koff];
        }
    }

    // main loop: 64 chunks of 16 codes; packed top-2 per (lane, rt)
    unsigned m1[4] = {~0u, ~0u, ~0u, ~0u}, m2[4] = {~0u, ~0u, ~0u, ~0u};
    for (int c = 0; c < 64; ++c) {
        const size_t abase = (size_t)(c * 16 + col) * DDIM + grp * 8;
        const bf16x8 wh0 = *(const bf16x8*)(wh + abase);
        const bf16x8 wh1 = *(const bf16x8*)(wh + abase + 32);
        const bf16x8 wl0 = *(const bf16x8*)(wl + abase);
        const bf16x8 wl1 = *(const bf16x8*)(wl + abase + 32);
        const float4 w2v = *(const float4*)&w2s[c * 16 + grp * 4];
#pragma unroll
        for (int rt = 0; rt < 4; ++rt) {
            f32x4 acc = {0.f, 0.f, 0.f, 0.f};
            acc = __builtin_amdgcn_mfma_f32_16x16x32_bf16(wh0, fxh[rt][0], acc, 0, 0, 0);
            acc = __builtin_amdgcn_mfma_f32_16x16x32_bf16(wh1, fxh[rt][1], acc, 0, 0, 0);
            acc = __builtin_amdgcn_mfma_f32_16x16x32_bf16(wl0, fxh[rt][0], acc, 0, 0, 0);
            acc = __builtin_amdgcn_mfma_f32_16x16x32_bf16(wl1, fxh[rt][1], acc, 0, 0, 0);
            acc = __builtin_amdgcn_mfma_f32_16x16x32_bf16(wh0, fxl[rt][0], acc, 0, 0, 0);
            acc = __builtin_amdgcn_mfma_f32_16x16x32_bf16(wh1, fxl[rt][1], acc, 0, 0, 0);
            const float* w2p = (const float*)&w2v;
#pragma unroll
            for (int r = 0; r < 4; ++r) {
                const float val = fmaf(-2.f, acc[r], w2p[r]);
                const unsigned code = (unsigned)(c * 16 + grp * 4 + r);
                const unsigned u = (flipf(val) & 0xFFFFFC00u) | code;
                const unsigned mx = m1[rt] > u ? m1[rt] : u;
                m1[rt] = m1[rt] < u ? m1[rt] : u;
                m2[rt] = m2[rt] < mx ? m2[rt] : mx;
            }
        }
    }

    // merge top-2 across the 4 lanes sharing each x-row
#pragma unroll
    for (int rt = 0; rt < 4; ++rt) {
        for (int off = 16; off <= 32; off <<= 1) {
            const unsigned o1 = (unsigned)__shfl_xor((int)m1[rt], off, 64);
            const unsigned o2 = (unsigned)__shfl_xor((int)m2[rt], off, 64);
            const unsigned mx = m1[rt] > o1 ? m1[rt] : o1;
            m1[rt] = m1[rt] < o1 ? m1[rt] : o1;
            const unsigned t = m2[rt] < o2 ? m2[rt] : o2;
            m2[rt] = t < mx ? t : mx;
        }
    }

    int k1rt[4];
    bool flag[4];
#pragma unroll
    for (int rt = 0; rt < 4; ++rt) {
        k1rt[rt] = (int)(m1[rt] & 1023u);
        flag[rt] = (grp == 0) && ((unflip_val(m2[rt]) - unflip_val(m1[rt])) < GAPTHR);
    }

    // near-tie rows: np-exact f32 rescan (same arithmetic as verified round 5)
    for (int rt = 0; rt < 4; ++rt) {
        unsigned long long need = __ballot(flag[rt]);
        while (need) {
            const int src = __ffsll(need) - 1;
            need &= need - 1;
            const int nr = blockIdx.x * 256 + wid * 64 + rt * 16 + src;
            const int wq = nr & 63, hq = (nr >> 6) & 63, bq = nr >> 12;
            const float xv = z[(size_t)bq * DDIM * HW + (size_t)lane * HW + hq * 64 + wq];
            // np-exact ||x||^2 cooperatively: lane j of 8 accumulates
            // v[j],v[8+j],... sequentially, then pairwise combine tree.
            const float p = mul_rn(xv, xv);
            float r = 0.f;
            for (int i = 0; i < 8; ++i) {
                const float t = __shfl(p, (i << 3) + (lane & 7), 64);
                r = add_rn(r, t);   // bare add; shuffle is opaque to fusion
            }
            const float s01 = add_rn(r, __shfl_xor(r, 1, 64));
            const float s03 = add_rn(s01, __shfl_xor(s01, 2, 64));
            const float s07 = add_rn(s03, __shfl_xor(s03, 4, 64));
            const float x2s = __shfl(s07, 0, 64);

            float acc[16];
#pragma unroll
            for (int j = 0; j < 16; ++j) acc[j] = 0.f;
            for (int d = 0; d < DDIM; ++d) {
                const float xd = __shfl(xv, d, 64);
#pragma unroll
                for (int j = 0; j < 16; ++j)
                    acc[j] = fmaf(emb[(size_t)(lane + 64 * j) * DDIM + d], xd, acc[j]);
            }
            float bv = 1e30f;
            int bk = KCODES;
#pragma unroll
            for (int j = 0; j < 16; ++j) {
                const int kk = lane + 64 * j;
                const float s  = add_rn(x2s, w2s[kk]);
                const float dv = sub2_rn(s, acc[j]);
                if (dv < bv) { bv = dv; bk = kk; }
            }
            for (int off = 32; off > 0; off >>= 1) {
                const float ov = __shfl_xor(bv, off, 64);
                const int   ok = __shfl_xor(bk, off, 64);
                if (ov < bv || (ov == bv && ok < bk)) { bv = ov; bk = ok; }
            }
            if (lane == src) k1rt[rt] = bk;
        }
    }

    // stash per-row winners (same-wave LDS region)
    if (grp == 0) {
#pragma unroll
        for (int rt = 0; rt < 4; ++rt)
            k1s[wid * 64 + rt * 16 + col] = (unsigned)k1rt[rt];
    }
    __syncthreads();

    // ---- phase A: lane = row. idx, cnt, z_q (coalesced), loss ----
    const unsigned myk = k1s[wid * 64 + lane];
    out[OFF_IDX + (size_t)(unsigned)n0] = (float)myk;
    atomicAdd(&cnt[myk], 1u);

    const float* wrow = emb + (size_t)myk * DDIM;
    float* ozb = out + (size_t)b0 * DDIM * HW + h0 * 64 + w0;
    float ls = 0.f;
#pragma unroll 4
    for (int d = 0; d < DDIM; d += 4) {
        const float4 wv = *(const float4*)(wrow + d);
        const float xa = bfu2f(sxh[tid][d+0]) + bfu2f(sxl[tid][d+0]);
        const float xb = bfu2f(sxh[tid][d+1]) + bfu2f(sxl[tid][d+1]);
        const float xc = bfu2f(sxh[tid][d+2]) + bfu2f(sxl[tid][d+2]);
        const float xd = bfu2f(sxh[tid][d+3]) + bfu2f(sxl[tid][d+3]);
        ozb[(size_t)(d+0) * HW] = wv.x;
        ozb[(size_t)(d+1) * HW] = wv.y;
        ozb[(size_t)(d+2) * HW] = wv.z;
        ozb[(size_t)(d+3) * HW] = wv.w;
        float a = xa - wv.x, b = xb - wv.y, c = xc - wv.z, e = xd - wv.w;
        ls = fmaf(a, a, ls); ls = fmaf(b, b, ls);
        ls = fmaf(c, c, ls); ls = fmaf(e, e, ls);
    }
#pragma unroll
    for (int off = 32; off > 0; off >>= 1) ls += __shfl_down(ls, off, 64);
    if (lane == 0) atomicAdd(lossAcc, ls);

    // ---- phase B: lane = d. coalesced esum atomics (64 consecutive addrs) ----
    for (int r = 0; r < 64; ++r) {
        const unsigned kr = (unsigned)__shfl((int)myk, r, 64);
        const int row = wid * 64 + r;
        const float xa = bfu2f(sxh[row][lane]) + bfu2f(sxl[row][lane]);
        atomicAdd(&esum[(size_t)kr * DDIM + lane], xa);
    }
}

__global__ __launch_bounds__(1024) void finalize_kernel(
        const float* __restrict__ cs, const float* __restrict__ eavg,
        float* __restrict__ out,
        const float* __restrict__ esum, const unsigned int* __restrict__ cnt,
        const float* __restrict__ lossAcc) {
    const int k = threadIdx.x;

    float es[DDIM];
#pragma unroll
    for (int d = 0; d < DDIM; ++d) es[d] = esum[(size_t)k * DDIM + d];
    const float cntk = (float)cnt[k];
    const float lossv = lossAcc[0];
    const float ncs = fmaf(0.01f, cntk, 0.99f * cs[k]);

    __shared__ float red[1024];
    red[k] = ncs;
    __syncthreads();
    for (int s = 512; s > 0; s >>= 1) {
        if (k < s) red[k] += red[k + s];
        __syncthreads();
    }
    const float nn = red[0];
    const float smoothed = (ncs + 1e-5f) / (nn + 1024.f * 1e-5f) * nn;

    out[OFF_NCS + (size_t)k] = ncs;
#pragma unroll
    for (int d = 0; d < DDIM; ++d) {
        const float ea = fmaf(0.01f, es[d], 0.99f * eavg[(size_t)k * DDIM + d]);
        out[OFF_EAVG + (size_t)k * DDIM + d] = ea;
        out[OFF_EMB  + (size_t)k * DDIM + d] = ea / smoothed;
    }
    if (k == 0)
        out[OFF_LOSS] = 0.25f * lossv / 8388608.f;
}

extern "C" void kernel_launch(void* const* d_in, const int* in_sizes, int n_in,
                              void* d_out, int out_size, void* d_ws, size_t ws_size,
                              hipStream_t stream) {
    const float* z    = (const float*)d_in[0];
    const float* emb  = (const float*)d_in[1];
    const float* cs   = (const float*)d_in[2];
    const float* eavg = (const float*)d_in[3];
    float* out = (float*)d_out;

    float*          esum = (float*)((char*)d_out + SCR_B0);
    unsigned int*   cnt  = (unsigned int*)((char*)d_out + SCR_CNT);
    unsigned short* wh   = (unsigned short*)((char*)d_out + SCR_WH);
    unsigned short* wl   = (unsigned short*)((char*)d_out + SCR_WL);
    float*          lossA = out + OFF_LOSS;

    (void)hipMemsetAsync((char*)d_out + SCR_B0, 0, 266240, stream);
    prep_kernel<<<4, 256, 0, stream>>>(emb, out, wh, wl);
    assign_kernel<<<NROWS / 256, 256, 0, stream>>>(z, emb, out, wh, wl, esum, cnt, lossA);
    finalize_kernel<<<1, 1024, 0, stream>>>(cs, eavg, out, esum, cnt, lossA);
}

// Round 8
// 389.855 us; speedup vs baseline: 3.6948x; 1.5900x over previous
//
#include <hip/hip_runtime.h>
#include <hip/hip_bf16.h>

#define NROWS 131072
#define DDIM  64
#define KCODES 1024
#define HW    4096

// d_out is FLOAT32. Element offsets (reference return order):
#define OFF_ZQ   0ull
#define OFF_IDX  8388608ull
#define OFF_LOSS 8519680ull
#define OFF_EMB  8519681ull
#define OFF_NCS  8585217ull
#define OFF_EAVG 8586241ull

// d_out scratch (over emb-output region; finalize2 rewrites it):
//   wh bf16[65536] @ SCR_B0, wl bf16[65536] @ +131072, w2 f32[1024] @ +262144
#define SCR_B0   34078724ull
#define SCR_WLO  (SCR_B0 + 131072ull)
#define SCR_W2O  (SCR_B0 + 262144ull)

// Legacy (round-7, proven) layout when d_ws is too small:
#define LSCR_ESUM SCR_B0
#define LSCR_CNT  (SCR_B0 + 262144ull)
#define LSCR_WH   (SCR_B0 + 266240ull)
#define LSCR_WL   (SCR_B0 + 397312ull)

#define GAPTHR  7e-5f
#define LGAPTHR 6e-5f

typedef __attribute__((ext_vector_type(8))) short bf16x8;
typedef __attribute__((ext_vector_type(4))) float f32x4;

__device__ __forceinline__ float np_sumsq64(const float* v) {
#pragma clang fp contract(off)
    float r0 = v[0]*v[0], r1 = v[1]*v[1], r2 = v[2]*v[2], r3 = v[3]*v[3];
    float r4 = v[4]*v[4], r5 = v[5]*v[5], r6 = v[6]*v[6], r7 = v[7]*v[7];
    for (int i = 8; i < 64; i += 8) {
        r0 += v[i+0]*v[i+0]; r1 += v[i+1]*v[i+1];
        r2 += v[i+2]*v[i+2]; r3 += v[i+3]*v[i+3];
        r4 += v[i+4]*v[i+4]; r5 += v[i+5]*v[i+5];
        r6 += v[i+6]*v[i+6]; r7 += v[i+7]*v[i+7];
    }
    return ((r0+r1)+(r2+r3))+((r4+r5)+(r6+r7));
}
__device__ __forceinline__ float mul_rn(float a, float b) {
#pragma clang fp contract(off)
    return a * b;
}
__device__ __forceinline__ float add_rn(float a, float b) {
#pragma clang fp contract(off)
    return a + b;
}
__device__ __forceinline__ float sub2_rn(float s, float a) {
#pragma clang fp contract(off)
    return s - 2.0f * a;
}
__device__ __forceinline__ unsigned bf16rne(float v) {
    unsigned b = __float_as_uint(v);
    return (b + 0x7FFFu + ((b >> 16) & 1u)) >> 16;
}
__device__ __forceinline__ float bfu2f(unsigned short u) {
    return __uint_as_float(((unsigned)u) << 16);
}
__device__ __forceinline__ unsigned flipf(float v) {
    unsigned b = __float_as_uint(v);
    return b ^ (0x80000000u | (unsigned)((int)b >> 31));
}
__device__ __forceinline__ float unflip_val(unsigned u) {
    u &= 0xFFFFFC00u;
    unsigned mask = 0x80000000u | (unsigned)((int)(~u) >> 31);
    return __uint_as_float(u ^ mask);
}

// ============================ WS (fast) PATH ============================

__global__ __launch_bounds__(256) void prep_kernel(
        const float* __restrict__ emb, unsigned short* __restrict__ wh,
        unsigned short* __restrict__ wl, float* __restrict__ w2,
        float* __restrict__ embT) {
    __shared__ float tile[64][65];
    const int t = threadIdx.x;
    const int kb = blockIdx.x * 64;
#pragma unroll
    for (int i = 0; i < 16; ++i) {
        const int e = t + i * 256;
        const int kl = e >> 6, d = e & 63;
        const float v = emb[(size_t)(kb + kl) * DDIM + d];
        tile[kl][d] = v;
        const unsigned rh = bf16rne(v);
        const float lv = v - bfu2f((unsigned short)rh);
        wh[(size_t)(kb + kl) * DDIM + d] = (unsigned short)rh;
        wl[(size_t)(kb + kl) * DDIM + d] = (unsigned short)bf16rne(lv);
    }
    __syncthreads();
    if (t < 64) w2[kb + t] = np_sumsq64(&tile[t][0]);
#pragma unroll
    for (int i = 0; i < 16; ++i) {
        const int e = t + i * 256;
        const int d = e >> 6, kl = e & 63;
        embT[(size_t)d * KCODES + kb + kl] = tile[kl][d];
    }
}

__global__ __launch_bounds__(256, 3) void assign_kernel(
        const float* __restrict__ z, const float* __restrict__ emb,
        float* __restrict__ out,
        const unsigned short* __restrict__ wh, const unsigned short* __restrict__ wl,
        const float* __restrict__ w2, const float* __restrict__ embT,
        float* __restrict__ esum_p, unsigned int* __restrict__ cnt_p,
        float* __restrict__ lossAcc, int pmask) {
    __shared__ unsigned short sx[256][72];
    __shared__ float w2s[KCODES];
    __shared__ unsigned k1s[256];
    __shared__ float redl[4];

    const int tid = threadIdx.x;
    const int lane = tid & 63, wid = tid >> 6;
    const int col = lane & 15, grp = lane >> 4;

    for (int i = tid; i < KCODES; i += 256) w2s[i] = w2[i];

    const int n0 = blockIdx.x * 256 + tid;
    const int w0 = n0 & 63, h0 = (n0 >> 6) & 63, b0 = n0 >> 12;
    const float* zb = z + (size_t)b0 * DDIM * HW + h0 * 64 + w0;
    for (int d = 0; d < DDIM; ++d)
        sx[tid][d] = (unsigned short)bf16rne(zb[(size_t)d * HW]);
    __syncthreads();

    bf16x8 fxh[4][2];
#pragma unroll
    for (int rt = 0; rt < 4; ++rt) {
        const int row = wid * 64 + rt * 16 + col;
#pragma unroll
        for (int kh = 0; kh < 2; ++kh)
            fxh[rt][kh] = *(const bf16x8*)&sx[row][grp * 8 + kh * 32];
    }

    // main scan: exact top-2 (value + first-index winner) per (lane, rt)
    float m1[4] = {1e30f, 1e30f, 1e30f, 1e30f};
    float m2[4] = {1e30f, 1e30f, 1e30f, 1e30f};
    int   i1[4] = {0, 0, 0, 0};
#pragma unroll 2
    for (int c = 0; c < 64; ++c) {
        const size_t abase = (size_t)(c * 16 + col) * DDIM + grp * 8;
        const bf16x8 vh0 = *(const bf16x8*)(wh + abase);
        const bf16x8 vh1 = *(const bf16x8*)(wh + abase + 32);
        const bf16x8 vl0 = *(const bf16x8*)(wl + abase);
        const bf16x8 vl1 = *(const bf16x8*)(wl + abase + 32);
        const float4 w2v = *(const float4*)&w2s[c * 16 + grp * 4];
        const float* w2p = (const float*)&w2v;
#pragma unroll
        for (int rt = 0; rt < 4; ++rt) {
            f32x4 acc = {0.f, 0.f, 0.f, 0.f};
            acc = __builtin_amdgcn_mfma_f32_16x16x32_bf16(vh0, fxh[rt][0], acc, 0, 0, 0);
            acc = __builtin_amdgcn_mfma_f32_16x16x32_bf16(vh1, fxh[rt][1], acc, 0, 0, 0);
            acc = __builtin_amdgcn_mfma_f32_16x16x32_bf16(vl0, fxh[rt][0], acc, 0, 0, 0);
            acc = __builtin_amdgcn_mfma_f32_16x16x32_bf16(vl1, fxh[rt][1], acc, 0, 0, 0);
#pragma unroll
            for (int r = 0; r < 4; ++r) {
                const float val = fmaf(-2.f, acc[r], w2p[r]);
                const int code = c * 16 + grp * 4 + r;
                const bool c1 = val < m1[rt];
                m2[rt] = c1 ? m1[rt] : fminf(m2[rt], val);
                i1[rt] = c1 ? code : i1[rt];
                m1[rt] = c1 ? val : m1[rt];
            }
        }
    }

    // merge top-2 across the 4 lanes sharing each x-row (idx tiebreak: lowest)
#pragma unroll
    for (int rt = 0; rt < 4; ++rt) {
        for (int off = 16; off <= 32; off <<= 1) {
            const float o1 = __shfl_xor(m1[rt], off, 64);
            const float o2 = __shfl_xor(m2[rt], off, 64);
            const int   oi = __shfl_xor(i1[rt], off, 64);
            const float mx = fmaxf(m1[rt], o1);
            const bool take = (o1 < m1[rt]) || (o1 == m1[rt] && oi < i1[rt]);
            i1[rt] = take ? oi : i1[rt];
            m1[rt] = take ? o1 : m1[rt];
            m2[rt] = fminf(fminf(m2[rt], o2), mx);
        }
    }

    int k1rt[4];
    bool flag[4];
#pragma unroll
    for (int rt = 0; rt < 4; ++rt) {
        k1rt[rt] = i1[rt];
        flag[rt] = (grp == 0) && ((m2[rt] - m1[rt]) < GAPTHR);
    }

    // flagged rows: full np-exact f32 rescan, coalesced via embT
    for (int rt = 0; rt < 4; ++rt) {
        unsigned long long need = __ballot(flag[rt]);
        while (need) {
            const int src = __ffsll(need) - 1;
            need &= need - 1;
            const int nr = blockIdx.x * 256 + wid * 64 + rt * 16 + src;
            const int wq = nr & 63, hq = (nr >> 6) & 63, bq = nr >> 12;
            const float xv = z[(size_t)bq * DDIM * HW + (size_t)lane * HW + hq * 64 + wq];
            const float p = mul_rn(xv, xv);
            float r = 0.f;
            for (int i = 0; i < 8; ++i) {
                const float t = __shfl(p, (i << 3) + (lane & 7), 64);
                r = add_rn(r, t);
            }
            const float s01 = add_rn(r, __shfl_xor(r, 1, 64));
            const float s03 = add_rn(s01, __shfl_xor(s01, 2, 64));
            const float s07 = add_rn(s03, __shfl_xor(s03, 4, 64));
            const float x2s = __shfl(s07, 0, 64);

            float acc[16];
#pragma unroll
            for (int j = 0; j < 16; ++j) acc[j] = 0.f;
            for (int d = 0; d < DDIM; ++d) {
                const float xd = __shfl(xv, d, 64);
                const float* ecol = embT + (size_t)d * KCODES + lane;
#pragma unroll
                for (int j = 0; j < 16; ++j)
                    acc[j] = fmaf(ecol[64 * j], xd, acc[j]);
            }
            float bv = 1e30f;
            int bk = KCODES;
#pragma unroll
            for (int j = 0; j < 16; ++j) {
                const int kk = lane + 64 * j;
                const float s  = add_rn(x2s, w2s[kk]);
                const float dv = sub2_rn(s, acc[j]);
                if (dv < bv) { bv = dv; bk = kk; }
            }
            for (int off = 32; off > 0; off >>= 1) {
                const float ov = __shfl_xor(bv, off, 64);
                const int   ok = __shfl_xor(bk, off, 64);
                if (ov < bv || (ov == bv && ok < bk)) { bv = ov; bk = ok; }
            }
            if (lane == src) k1rt[rt] = bk;
        }
    }

    if (grp == 0) {
#pragma unroll
        for (int rt = 0; rt < 4; ++rt)
            k1s[wid * 64 + rt * 16 + col] = (unsigned)k1rt[rt];
    }
    __syncthreads();

    const int part = blockIdx.x & pmask;

    // phase A: lane = row. idx, cnt, z_q, loss (hi-only x is plenty accurate)
    const unsigned myk = k1s[wid * 64 + lane];
    out[OFF_IDX + (size_t)(unsigned)n0] = (float)myk;
    atomicAdd(&cnt_p[part * KCODES + myk], 1u);

    const float* wrow = emb + (size_t)myk * DDIM;
    float* ozb = out + (size_t)b0 * DDIM * HW + h0 * 64 + w0;
    float ls = 0.f;
#pragma unroll 4
    for (int d = 0; d < DDIM; d += 4) {
        const float4 wv = *(const float4*)(wrow + d);
        const float xa = bfu2f(sx[tid][d+0]);
        const float xb = bfu2f(sx[tid][d+1]);
        const float xc = bfu2f(sx[tid][d+2]);
        const float xd = bfu2f(sx[tid][d+3]);
        ozb[(size_t)(d+0) * HW] = wv.x;
        ozb[(size_t)(d+1) * HW] = wv.y;
        ozb[(size_t)(d+2) * HW] = wv.z;
        ozb[(size_t)(d+3) * HW] = wv.w;
        float a = xa - wv.x, b = xb - wv.y, c = xc - wv.z, e = xd - wv.w;
        ls = fmaf(a, a, ls); ls = fmaf(b, b, ls);
        ls = fmaf(c, c, ls); ls = fmaf(e, e, ls);
    }
#pragma unroll
    for (int off = 32; off > 0; off >>= 1) ls += __shfl_down(ls, off, 64);
    if (lane == 0) redl[wid] = ls;
    __syncthreads();
    if (tid == 0) atomicAdd(lossAcc, redl[0] + redl[1] + redl[2] + redl[3]);

    // phase B: lane = d. privatized coalesced esum atomics
    float* ep = esum_p + (size_t)part * 65536;
    for (int r = 0; r < 64; ++r) {
        const unsigned kr = (unsigned)__shfl((int)myk, r, 64);
        const float xa = bfu2f(sx[wid * 64 + r][lane]);
        atomicAdd(&ep[(size_t)kr * DDIM + lane], xa);
    }
}

__global__ __launch_bounds__(1024) void finalize1_kernel(
        const float* __restrict__ cs, float* __restrict__ out,
        const unsigned int* __restrict__ cnt_p, const float* __restrict__ lossAcc,
        float* __restrict__ smoothed, int P) {
    const int k = threadIdx.x;
    unsigned c = 0;
    for (int p = 0; p < P; ++p) c += cnt_p[p * KCODES + k];
    const float cntk = (float)c;
    const float ncs = fmaf(0.01f, cntk, 0.99f * cs[k]);

    __shared__ float red[1024];
    red[k] = ncs;
    __syncthreads();
    for (int s = 512; s > 0; s >>= 1) {
        if (k < s) red[k] += red[k + s];
        __syncthreads();
    }
    const float nn = red[0];
    smoothed[k] = (ncs + 1e-5f) / (nn + 1024.f * 1e-5f) * nn;
    out[OFF_NCS + (size_t)k] = ncs;
    if (k == 0) out[OFF_LOSS] = 0.25f * lossAcc[0] / 8388608.f;
}

__global__ __launch_bounds__(256) void finalize2_kernel(
        const float* __restrict__ eavg, float* __restrict__ out,
        const float* __restrict__ esum_p, const float* __restrict__ smoothed,
        int P) {
    const int e = blockIdx.x * 256 + threadIdx.x;   // 0..65535
    const int k = e >> 6;
    float s = 0.f;
    for (int p = 0; p < P; ++p) s += esum_p[(size_t)p * 65536 + e];
    const float ea = fmaf(0.01f, s, 0.99f * eavg[e]);
    out[OFF_EAVG + (size_t)e] = ea;
    out[OFF_EMB  + (size_t)e] = ea / smoothed[k];
}

// ===================== LEGACY PATH (round-7 verbatim) =====================

__global__ __launch_bounds__(256) void prep_kernel_l(
        const float* __restrict__ emb, float* __restrict__ out,
        unsigned short* __restrict__ wh, unsigned short* __restrict__ wl) {
    const int k = blockIdx.x * 256 + threadIdx.x;
    const float* w = emb + k * DDIM;
    for (int d = 0; d < DDIM; ++d) {
        const float v = w[d];
        const unsigned rh = bf16rne(v);
        const float lv = v - bfu2f((unsigned short)rh);
        wh[k * DDIM + d] = (unsigned short)rh;
        wl[k * DDIM + d] = (unsigned short)bf16rne(lv);
    }
    if (k == 0) out[OFF_LOSS] = 0.f;
}

__global__ __launch_bounds__(256, 2) void assign_kernel_l(
        const float* __restrict__ z, const float* __restrict__ emb,
        float* __restrict__ out,
        const unsigned short* __restrict__ wh, const unsigned short* __restrict__ wl,
        float* __restrict__ esum, unsigned int* __restrict__ cnt,
        float* __restrict__ lossAcc) {
    __shared__ unsigned short sxh[256][72];
    __shared__ unsigned short sxl[256][72];
    __shared__ float w2s[KCODES];
    __shared__ unsigned k1s[256];

    const int tid = threadIdx.x;
    const int lane = tid & 63, wid = tid >> 6;
    const int col = lane & 15, grp = lane >> 4;

    for (int r = 0; r < 4; ++r) {
        const int c = tid + 256 * r;
        w2s[c] = np_sumsq64(emb + c * DDIM);
    }
    const int n0 = blockIdx.x * 256 + tid;
    const int w0 = n0 & 63, h0 = (n0 >> 6) & 63, b0 = n0 >> 12;
    {
        const float* zb = z + (size_t)b0 * DDIM * HW + h0 * 64 + w0;
        for (int d = 0; d < DDIM; ++d) {
            const float v = zb[(size_t)d * HW];
            const unsigned rh = bf16rne(v);
            const float lv = v - bfu2f((unsigned short)rh);
            sxh[tid][d] = (unsigned short)rh;
            sxl[tid][d] = (unsigned short)bf16rne(lv);
        }
    }
    __syncthreads();

    bf16x8 fxh[4][2], fxl[4][2];
#pragma unroll
    for (int rt = 0; rt < 4; ++rt) {
        const int row = wid * 64 + rt * 16 + col;
#pragma unroll
        for (int kh = 0; kh < 2; ++kh) {
            const int koff = grp * 8 + kh * 32;
            fxh[rt][kh] = *(const bf16x8*)&sxh[row][koff];
            fxl[rt][kh] = *(const bf16x8*)&sxl[row][koff];
        }
    }

    unsigned m1[4] = {~0u, ~0u, ~0u, ~0u}, m2[4] = {~0u, ~0u, ~0u, ~0u};
    for (int c = 0; c < 64; ++c) {
        const size_t abase = (size_t)(c * 16 + col) * DDIM + grp * 8;
        const bf16x8 vh0 = *(const bf16x8*)(wh + abase);
        const bf16x8 vh1 = *(const bf16x8*)(wh + abase + 32);
        const bf16x8 vl0 = *(const bf16x8*)(wl + abase);
        const bf16x8 vl1 = *(const bf16x8*)(wl + abase + 32);
        const float4 w2v = *(const float4*)&w2s[c * 16 + grp * 4];
#pragma unroll
        for (int rt = 0; rt < 4; ++rt) {
            f32x4 acc = {0.f, 0.f, 0.f, 0.f};
            acc = __builtin_amdgcn_mfma_f32_16x16x32_bf16(vh0, fxh[rt][0], acc, 0, 0, 0);
            acc = __builtin_amdgcn_mfma_f32_16x16x32_bf16(vh1, fxh[rt][1], acc, 0, 0, 0);
            acc = __builtin_amdgcn_mfma_f32_16x16x32_bf16(vl0, fxh[rt][0], acc, 0, 0, 0);
            acc = __builtin_amdgcn_mfma_f32_16x16x32_bf16(vl1, fxh[rt][1], acc, 0, 0, 0);
            acc = __builtin_amdgcn_mfma_f32_16x16x32_bf16(vh0, fxl[rt][0], acc, 0, 0, 0);
            acc = __builtin_amdgcn_mfma_f32_16x16x32_bf16(vh1, fxl[rt][1], acc, 0, 0, 0);
            const float* w2p = (const float*)&w2v;
#pragma unroll
            for (int r = 0; r < 4; ++r) {
                const float val = fmaf(-2.f, acc[r], w2p[r]);
                const unsigned code = (unsigned)(c * 16 + grp * 4 + r);
                const unsigned u = (flipf(val) & 0xFFFFFC00u) | code;
                const unsigned mx = m1[rt] > u ? m1[rt] : u;
                m1[rt] = m1[rt] < u ? m1[rt] : u;
                m2[rt] = m2[rt] < mx ? m2[rt] : mx;
            }
        }
    }
#pragma unroll
    for (int rt = 0; rt < 4; ++rt) {
        for (int off = 16; off <= 32; off <<= 1) {
            const unsigned o1 = (unsigned)__shfl_xor((int)m1[rt], off, 64);
            const unsigned o2 = (unsigned)__shfl_xor((int)m2[rt], off, 64);
            const unsigned mx = m1[rt] > o1 ? m1[rt] : o1;
            m1[rt] = m1[rt] < o1 ? m1[rt] : o1;
            const unsigned t = m2[rt] < o2 ? m2[rt] : o2;
            m2[rt] = t < mx ? t : mx;
        }
    }
    int k1rt[4];
    bool flag[4];
#pragma unroll
    for (int rt = 0; rt < 4; ++rt) {
        k1rt[rt] = (int)(m1[rt] & 1023u);
        flag[rt] = (grp == 0) && ((unflip_val(m2[rt]) - unflip_val(m1[rt])) < LGAPTHR);
    }
    for (int rt = 0; rt < 4; ++rt) {
        unsigned long long need = __ballot(flag[rt]);
        while (need) {
            const int src = __ffsll(need) - 1;
            need &= need - 1;
            const int nr = blockIdx.x * 256 + wid * 64 + rt * 16 + src;
            const int wq = nr & 63, hq = (nr >> 6) & 63, bq = nr >> 12;
            const float xv = z[(size_t)bq * DDIM * HW + (size_t)lane * HW + hq * 64 + wq];
            const float p = mul_rn(xv, xv);
            float r = 0.f;
            for (int i = 0; i < 8; ++i) {
                const float t = __shfl(p, (i << 3) + (lane & 7), 64);
                r = add_rn(r, t);
            }
            const float s01 = add_rn(r, __shfl_xor(r, 1, 64));
            const float s03 = add_rn(s01, __shfl_xor(s01, 2, 64));
            const float s07 = add_rn(s03, __shfl_xor(s03, 4, 64));
            const float x2s = __shfl(s07, 0, 64);

            float acc[16];
#pragma unroll
            for (int j = 0; j < 16; ++j) acc[j] = 0.f;
            for (int d = 0; d < DDIM; ++d) {
                const float xd = __shfl(xv, d, 64);
#pragma unroll
                for (int j = 0; j < 16; ++j)
                    acc[j] = fmaf(emb[(size_t)(lane + 64 * j) * DDIM + d], xd, acc[j]);
            }
            float bv = 1e30f;
            int bk = KCODES;
#pragma unroll
            for (int j = 0; j < 16; ++j) {
                const int kk = lane + 64 * j;
                const float s  = add_rn(x2s, w2s[kk]);
                const float dv = sub2_rn(s, acc[j]);
                if (dv < bv) { bv = dv; bk = kk; }
            }
            for (int off = 32; off > 0; off >>= 1) {
                const float ov = __shfl_xor(bv, off, 64);
                const int   ok = __shfl_xor(bk, off, 64);
                if (ov < bv || (ov == bv && ok < bk)) { bv = ov; bk = ok; }
            }
            if (lane == src) k1rt[rt] = bk;
        }
    }
    if (grp == 0) {
#pragma unroll
        for (int rt = 0; rt < 4; ++rt)
            k1s[wid * 64 + rt * 16 + col] = (unsigned)k1rt[rt];
    }
    __syncthreads();

    const unsigned myk = k1s[wid * 64 + lane];
    out[OFF_IDX + (size_t)(unsigned)n0] = (float)myk;
    atomicAdd(&cnt[myk], 1u);

    const float* wrow = emb + (size_t)myk * DDIM;
    float* ozb = out + (size_t)b0 * DDIM * HW + h0 * 64 + w0;
    float ls = 0.f;
#pragma unroll 4
    for (int d = 0; d < DDIM; d += 4) {
        const float4 wv = *(const float4*)(wrow + d);
        const float xa = bfu2f(sxh[tid][d+0]) + bfu2f(sxl[tid][d+0]);
        const float xb = bfu2f(sxh[tid][d+1]) + bfu2f(sxl[tid][d+1]);
        const float xc = bfu2f(sxh[tid][d+2]) + bfu2f(sxl[tid][d+2]);
        const float xd = bfu2f(sxh[tid][d+3]) + bfu2f(sxl[tid][d+3]);
        ozb[(size_t)(d+0) * HW] = wv.x;
        ozb[(size_t)(d+1) * HW] = wv.y;
        ozb[(size_t)(d+2) * HW] = wv.z;
        ozb[(size_t)(d+3) * HW] = wv.w;
        float a = xa - wv.x, b = xb - wv.y, c = xc - wv.z, e = xd - wv.w;
        ls = fmaf(a, a, ls); ls = fmaf(b, b, ls);
        ls = fmaf(c, c, ls); ls = fmaf(e, e, ls);
    }
#pragma unroll
    for (int off = 32; off > 0; off >>= 1) ls += __shfl_down(ls, off, 64);
    if (lane == 0) atomicAdd(lossAcc, ls);

    for (int r = 0; r < 64; ++r) {
        const unsigned kr = (unsigned)__shfl((int)myk, r, 64);
        const int row = wid * 64 + r;
        const float xa = bfu2f(sxh[row][lane]) + bfu2f(sxl[row][lane]);
        atomicAdd(&esum[(size_t)kr * DDIM + lane], xa);
    }
}

__global__ __launch_bounds__(1024) void finalize_kernel_l(
        const float* __restrict__ cs, const float* __restrict__ eavg,
        float* __restrict__ out,
        const float* __restrict__ esum, const unsigned int* __restrict__ cnt,
        const float* __restrict__ lossAcc) {
    const int k = threadIdx.x;
    float es[DDIM];
#pragma unroll
    for (int d = 0; d < DDIM; ++d) es[d] = esum[(size_t)k * DDIM + d];
    const float cntk = (float)cnt[k];
    const float lossv = lossAcc[0];
    const float ncs = fmaf(0.01f, cntk, 0.99f * cs[k]);

    __shared__ float red[1024];
    red[k] = ncs;
    __syncthreads();
    for (int s = 512; s > 0; s >>= 1) {
        if (k < s) red[k] += red[k + s];
        __syncthreads();
    }
    const float nn = red[0];
    const float smoothed = (ncs + 1e-5f) / (nn + 1024.f * 1e-5f) * nn;
    out[OFF_NCS + (size_t)k] = ncs;
#pragma unroll
    for (int d = 0; d < DDIM; ++d) {
        const float ea = fmaf(0.01f, es[d], 0.99f * eavg[(size_t)k * DDIM + d]);
        out[OFF_EAVG + (size_t)k * DDIM + d] = ea;
        out[OFF_EMB  + (size_t)k * DDIM + d] = ea / smoothed;
    }
    if (k == 0)
        out[OFF_LOSS] = 0.25f * lossv / 8388608.f;
}

// =========================================================================

extern "C" void kernel_launch(void* const* d_in, const int* in_sizes, int n_in,
                              void* d_out, int out_size, void* d_ws, size_t ws_size,
                              hipStream_t stream) {
    const float* z    = (const float*)d_in[0];
    const float* emb  = (const float*)d_in[1];
    const float* cs   = (const float*)d_in[2];
    const float* eavg = (const float*)d_in[3];
    float* out = (float*)d_out;

    int P = 0;
    for (int p = 16; p >= 1; p >>= 1)
        if (ws_size >= (size_t)p * 266240 + 266496) { P = p; break; }

    if (P) {
        char* ws = (char*)d_ws;
        float*        esum_p  = (float*)ws;
        unsigned int* cnt_p   = (unsigned int*)(ws + (size_t)P * 262144);
        float*        lossA   = (float*)(ws + (size_t)P * 266240);
        float*        smooth  = (float*)(ws + (size_t)P * 266240 + 256);
        float*        embT    = (float*)(ws + (size_t)P * 266240 + 256 + 4096);
        unsigned short* wh = (unsigned short*)((char*)d_out + SCR_B0);
        unsigned short* wl = (unsigned short*)((char*)d_out + SCR_WLO);
        float*          w2 = (float*)((char*)d_out + SCR_W2O);

        (void)hipMemsetAsync(ws, 0, (size_t)P * 266240 + 256, stream);
        prep_kernel<<<16, 256, 0, stream>>>(emb, wh, wl, w2, embT);
        assign_kernel<<<NROWS / 256, 256, 0, stream>>>(
            z, emb, out, wh, wl, w2, embT, esum_p, cnt_p, lossA, P - 1);
        finalize1_kernel<<<1, 1024, 0, stream>>>(cs, out, cnt_p, lossA, smooth, P);
        finalize2_kernel<<<256, 256, 0, stream>>>(eavg, out, esum_p, smooth, P);
    } else {
        float*          esum = (float*)((char*)d_out + LSCR_ESUM);
        unsigned int*   cnt  = (unsigned int*)((char*)d_out + LSCR_CNT);
        unsigned short* wh   = (unsigned short*)((char*)d_out + LSCR_WH);
        unsigned short* wl   = (unsigned short*)((char*)d_out + LSCR_WL);
        float*          lossA = out + OFF_LOSS;

        (void)hipMemsetAsync((char*)d_out + LSCR_ESUM, 0, 266240, stream);
        prep_kernel_l<<<4, 256, 0, stream>>>(emb, out, wh, wl);
        assign_kernel_l<<<NROWS / 256, 256, 0, stream>>>(z, emb, out, wh, wl, esum, cnt, lossA);
        finalize_kernel_l<<<1, 1024, 0, stream>>>(cs, eavg, out, esum, cnt, lossA);
    }
}

// Round 9
// 388.186 us; speedup vs baseline: 3.7107x; 1.0043x over previous
//
#include <hip/hip_runtime.h>
#include <hip/hip_bf16.h>

#define NROWS 131072
#define DDIM  64
#define KCODES 1024
#define HW    4096

// d_out is FLOAT32. Element offsets (reference return order):
#define OFF_ZQ   0ull
#define OFF_IDX  8388608ull
#define OFF_LOSS 8519680ull
#define OFF_EMB  8519681ull
#define OFF_NCS  8585217ull
#define OFF_EAVG 8586241ull

// d_out scratch over emb/ncs/eavg output region (rewritten by finalize1/2):
#define SCR_B0   34078724ull                 // wh bf16[65536]
#define SCR_WLO  (SCR_B0 + 131072ull)        // wl bf16[65536]
#define SCR_W2O  (SCR_B0 + 262144ull)        // w2 f32[1024]

#define GAPTHR 7e-5f

typedef __attribute__((ext_vector_type(8))) short bf16x8;
typedef __attribute__((ext_vector_type(4))) float f32x4;

#define GLOAD_LDS16(gp, lp)                                                     \
    __builtin_amdgcn_global_load_lds(                                           \
        (const __attribute__((address_space(1))) void*)(gp),                    \
        (__attribute__((address_space(3))) void*)(lp), 16, 0, 0)

__device__ __forceinline__ float np_sumsq64(const float* v) {
#pragma clang fp contract(off)
    float r0 = v[0]*v[0], r1 = v[1]*v[1], r2 = v[2]*v[2], r3 = v[3]*v[3];
    float r4 = v[4]*v[4], r5 = v[5]*v[5], r6 = v[6]*v[6], r7 = v[7]*v[7];
    for (int i = 8; i < 64; i += 8) {
        r0 += v[i+0]*v[i+0]; r1 += v[i+1]*v[i+1];
        r2 += v[i+2]*v[i+2]; r3 += v[i+3]*v[i+3];
        r4 += v[i+4]*v[i+4]; r5 += v[i+5]*v[i+5];
        r6 += v[i+6]*v[i+6]; r7 += v[i+7]*v[i+7];
    }
    return ((r0+r1)+(r2+r3))+((r4+r5)+(r6+r7));
}
__device__ __forceinline__ float mul_rn(float a, float b) {
#pragma clang fp contract(off)
    return a * b;
}
__device__ __forceinline__ float add_rn(float a, float b) {
#pragma clang fp contract(off)
    return a + b;
}
__device__ __forceinline__ float sub2_rn(float s, float a) {
#pragma clang fp contract(off)
    return s - 2.0f * a;
}
__device__ __forceinline__ unsigned bf16rne(float v) {
    unsigned b = __float_as_uint(v);
    return (b + 0x7FFFu + ((b >> 16) & 1u)) >> 16;
}
__device__ __forceinline__ float bfu2f(unsigned short u) {
    return __uint_as_float(((unsigned)u) << 16);
}

__global__ __launch_bounds__(256) void prep_kernel(
        const float* __restrict__ emb, unsigned short* __restrict__ wh,
        unsigned short* __restrict__ wl, float* __restrict__ w2,
        float* __restrict__ embT) {
    __shared__ float tile[64][65];
    const int t = threadIdx.x;
    const int kb = blockIdx.x * 64;
#pragma unroll
    for (int i = 0; i < 16; ++i) {
        const int e = t + i * 256;
        const int kl = e >> 6, d = e & 63;
        const float v = emb[(size_t)(kb + kl) * DDIM + d];
        tile[kl][d] = v;
        const unsigned rh = bf16rne(v);
        const float lv = v - bfu2f((unsigned short)rh);
        wh[(size_t)(kb + kl) * DDIM + d] = (unsigned short)rh;
        wl[(size_t)(kb + kl) * DDIM + d] = (unsigned short)bf16rne(lv);
    }
    __syncthreads();
    if (t < 64) w2[kb + t] = np_sumsq64(&tile[t][0]);
#pragma unroll
    for (int i = 0; i < 16; ++i) {
        const int e = t + i * 256;
        const int d = e >> 6, kl = e & 63;
        embT[(size_t)d * KCODES + kb + kl] = tile[kl][d];
    }
}

__global__ __launch_bounds__(512, 4) void assign_kernel(
        const float* __restrict__ z, const float* __restrict__ emb,
        float* __restrict__ out,
        const unsigned short* __restrict__ wh, const unsigned short* __restrict__ wl,
        const float* __restrict__ w2, const float* __restrict__ embT,
        float* __restrict__ esum_p, unsigned int* __restrict__ cnt_p,
        float* __restrict__ lossAcc, int pmask) {
    // sx: 256 rows x 72 (pad) bf16-hi of x. cb: [buf][pr][s*2+kh][64 words x 8]
    __shared__ __attribute__((aligned(16))) unsigned short sx[256][72];
    __shared__ __attribute__((aligned(16))) unsigned short cb[2][2][4][512];
    __shared__ float w2s[KCODES];
    __shared__ unsigned k1s[256];
    __shared__ float redl[8];

    const int tid = threadIdx.x;
    const int lane = tid & 63, wid = tid >> 6;
    const int col = lane & 15, grp = lane >> 4;
    const int nb = blockIdx.x * 256;

    for (int i = tid; i < KCODES; i += 512) w2s[i] = w2[i];

    // stage x rows (2 threads/row, 32 d each), bf16-hi only
    {
        const int row = tid & 255, dh = tid >> 8;
        const int n = nb + row;
        const int w0 = n & 63, h0 = (n >> 6) & 63, b0 = n >> 12;
        const float* zb = z + (size_t)b0 * DDIM * HW + (size_t)dh * 32 * HW + h0 * 64 + w0;
        for (int j = 0; j < 32; ++j)
            sx[row][dh * 32 + j] = (unsigned short)bf16rne(zb[(size_t)j * HW]);
    }
    __syncthreads();

    // x-side fragments: wave wid owns rows [wid*32, wid*32+32), rt in {0,1}
    bf16x8 fx[2][2];
#pragma unroll
    for (int rt = 0; rt < 2; ++rt)
#pragma unroll
        for (int kh = 0; kh < 2; ++kh)
            fx[rt][kh] = *(const bf16x8*)&sx[wid * 32 + rt * 16 + col][kh * 32 + grp * 8];

    // per-wave staging region: pr = hi/lo, sW = 16-code sub, khW = k-half
    const int pr = wid >> 2, sW = (wid >> 1) & 1, khW = wid & 1;
    const unsigned short* gsrc = (pr ? wl : wh) + khW * 32 + grp * 8
                               + (size_t)(sW * 16 + col) * DDIM;

    // prologue: stage round 0 into buf 0
    GLOAD_LDS16(gsrc, &cb[0][pr][sW * 2 + khW][0]);
    asm volatile("s_waitcnt vmcnt(0)" ::: "memory");
    __builtin_amdgcn_s_barrier();

    float m1[2] = {1e30f, 1e30f}, m2[2] = {1e30f, 1e30f};
    int   i1[2] = {0, 0};

    for (int rd = 0; rd < 32; ++rd) {
        const int cur = rd & 1;
        if (rd < 31)   // issue next round's stage (overlaps with compute)
            GLOAD_LDS16(gsrc + (size_t)(rd + 1) * 32 * DDIM,
                        &cb[cur ^ 1][pr][sW * 2 + khW][0]);
#pragma unroll
        for (int s = 0; s < 2; ++s) {
            const bf16x8 vh0 = *(const bf16x8*)&cb[cur][0][s * 2 + 0][lane * 8];
            const bf16x8 vh1 = *(const bf16x8*)&cb[cur][0][s * 2 + 1][lane * 8];
            const bf16x8 vl0 = *(const bf16x8*)&cb[cur][1][s * 2 + 0][lane * 8];
            const bf16x8 vl1 = *(const bf16x8*)&cb[cur][1][s * 2 + 1][lane * 8];
            const int cbase = rd * 32 + s * 16;
            const float4 w2v = *(const float4*)&w2s[cbase + grp * 4];
            const float* w2p = (const float*)&w2v;
#pragma unroll
            for (int rt = 0; rt < 2; ++rt) {
                f32x4 aA = {0.f, 0.f, 0.f, 0.f}, aB = {0.f, 0.f, 0.f, 0.f};
                aA = __builtin_amdgcn_mfma_f32_16x16x32_bf16(vh0, fx[rt][0], aA, 0, 0, 0);
                aA = __builtin_amdgcn_mfma_f32_16x16x32_bf16(vl0, fx[rt][0], aA, 0, 0, 0);
                aB = __builtin_amdgcn_mfma_f32_16x16x32_bf16(vh1, fx[rt][1], aB, 0, 0, 0);
                aB = __builtin_amdgcn_mfma_f32_16x16x32_bf16(vl1, fx[rt][1], aB, 0, 0, 0);
#pragma unroll
                for (int r = 0; r < 4; ++r) {
                    const float val = fmaf(-2.f, aA[r] + aB[r], w2p[r]);
                    const int code = cbase + grp * 4 + r;
                    const bool c1 = val < m1[rt];
                    m2[rt] = c1 ? m1[rt] : fminf(m2[rt], val);
                    i1[rt] = c1 ? code : i1[rt];
                    m1[rt] = c1 ? val : m1[rt];
                }
            }
        }
        asm volatile("s_waitcnt vmcnt(0) lgkmcnt(0)" ::: "memory");
        __builtin_amdgcn_s_barrier();
    }

    // merge top-2 across the 4 lanes (grp) sharing each x-row
#pragma unroll
    for (int rt = 0; rt < 2; ++rt) {
        for (int off = 16; off <= 32; off <<= 1) {
            const float o1 = __shfl_xor(m1[rt], off, 64);
            const float o2 = __shfl_xor(m2[rt], off, 64);
            const int   oi = __shfl_xor(i1[rt], off, 64);
            const float mx = fmaxf(m1[rt], o1);
            const bool take = (o1 < m1[rt]) || (o1 == m1[rt] && oi < i1[rt]);
            i1[rt] = take ? oi : i1[rt];
            m1[rt] = take ? o1 : m1[rt];
            m2[rt] = fminf(fminf(m2[rt], o2), mx);
        }
    }

    int k1rt[2];
    bool flag[2];
#pragma unroll
    for (int rt = 0; rt < 2; ++rt) {
        k1rt[rt] = i1[rt];
        flag[rt] = (grp == 0) && ((m2[rt] - m1[rt]) < GAPTHR);
    }

    // near-tie rows: full np-exact f32 rescan (coalesced via embT)
    for (int rt = 0; rt < 2; ++rt) {
        unsigned long long need = __ballot(flag[rt]);
        while (need) {
            const int src = __ffsll(need) - 1;
            need &= need - 1;
            const int nr = nb + wid * 32 + rt * 16 + src;
            const int wq = nr & 63, hq = (nr >> 6) & 63, bq = nr >> 12;
            const float xv = z[(size_t)bq * DDIM * HW + (size_t)lane * HW + hq * 64 + wq];
            const float p = mul_rn(xv, xv);
            float r = 0.f;
            for (int i = 0; i < 8; ++i) {
                const float t = __shfl(p, (i << 3) + (lane & 7), 64);
                r = add_rn(r, t);
            }
            const float s01 = add_rn(r, __shfl_xor(r, 1, 64));
            const float s03 = add_rn(s01, __shfl_xor(s01, 2, 64));
            const float s07 = add_rn(s03, __shfl_xor(s03, 4, 64));
            const float x2s = __shfl(s07, 0, 64);

            float acc[16];
#pragma unroll
            for (int j = 0; j < 16; ++j) acc[j] = 0.f;
            for (int d = 0; d < DDIM; ++d) {
                const float xd = __shfl(xv, d, 64);
                const float* ecol = embT + (size_t)d * KCODES + lane;
#pragma unroll
                for (int j = 0; j < 16; ++j)
                    acc[j] = fmaf(ecol[64 * j], xd, acc[j]);
            }
            float bv = 1e30f;
            int bk = KCODES;
#pragma unroll
            for (int j = 0; j < 16; ++j) {
                const int kk = lane + 64 * j;
                const float s  = add_rn(x2s, w2s[kk]);
                const float dv = sub2_rn(s, acc[j]);
                if (dv < bv) { bv = dv; bk = kk; }
            }
            for (int off = 32; off > 0; off >>= 1) {
                const float ov = __shfl_xor(bv, off, 64);
                const int   ok = __shfl_xor(bk, off, 64);
                if (ov < bv || (ov == bv && ok < bk)) { bv = ov; bk = ok; }
            }
            if (lane == src) k1rt[rt] = bk;
        }
    }

    if (grp == 0) {
#pragma unroll
        for (int rt = 0; rt < 2; ++rt)
            k1s[wid * 32 + rt * 16 + col] = (unsigned)k1rt[rt];
    }
    __syncthreads();

    const int part = blockIdx.x & pmask;

    // phase A: 2 threads/row (32 d each): idx, cnt, z_q, loss
    {
        const int rA = tid & 255, dhA = tid >> 8;
        const int nA = nb + rA;
        const int wA = nA & 63, hA = (nA >> 6) & 63, bA = nA >> 12;
        const unsigned myk = k1s[rA];
        if (dhA == 0) {
            out[OFF_IDX + (size_t)(unsigned)nA] = (float)myk;
            atomicAdd(&cnt_p[part * KCODES + myk], 1u);
        }
        const float* wrow = emb + (size_t)myk * DDIM + dhA * 32;
        float* ozb = out + (size_t)bA * DDIM * HW + (size_t)dhA * 32 * HW + hA * 64 + wA;
        float ls = 0.f;
#pragma unroll
        for (int j = 0; j < 32; j += 4) {
            const float4 wv = *(const float4*)(wrow + j);
            const ushort4 xu = *(const ushort4*)&sx[rA][dhA * 32 + j];
            ozb[(size_t)(j + 0) * HW] = wv.x;
            ozb[(size_t)(j + 1) * HW] = wv.y;
            ozb[(size_t)(j + 2) * HW] = wv.z;
            ozb[(size_t)(j + 3) * HW] = wv.w;
            const float a = bfu2f(xu.x) - wv.x, b = bfu2f(xu.y) - wv.y;
            const float c = bfu2f(xu.z) - wv.z, e = bfu2f(xu.w) - wv.w;
            ls = fmaf(a, a, ls); ls = fmaf(b, b, ls);
            ls = fmaf(c, c, ls); ls = fmaf(e, e, ls);
        }
#pragma unroll
        for (int off = 32; off > 0; off >>= 1) ls += __shfl_down(ls, off, 64);
        if (lane == 0) redl[wid] = ls;
    }
    __syncthreads();
    if (tid == 0) {
        float t = 0.f;
#pragma unroll
        for (int i = 0; i < 8; ++i) t += redl[i];
        atomicAdd(lossAcc, t);
    }

    // phase B: lane = d; privatized coalesced esum atomics (32 rows/wave)
    {
        float* ep = esum_p + (size_t)part * 65536;
        for (int r = 0; r < 32; ++r) {
            const int row = wid * 32 + r;
            const unsigned kr = k1s[row];
            const float xa = bfu2f(sx[row][lane]);
            atomicAdd(&ep[(size_t)kr * DDIM + lane], xa);
        }
    }
}

__global__ __launch_bounds__(1024) void finalize1_kernel(
        const float* __restrict__ cs, float* __restrict__ out,
        const unsigned int* __restrict__ cnt_p, const float* __restrict__ lossAcc,
        float* __restrict__ smoothed, int P) {
    const int k = threadIdx.x;
    unsigned c = 0;
    for (int p = 0; p < P; ++p) c += cnt_p[p * KCODES + k];
    const float cntk = (float)c;
    const float ncs = fmaf(0.01f, cntk, 0.99f * cs[k]);

    __shared__ float red[1024];
    red[k] = ncs;
    __syncthreads();
    for (int s = 512; s > 0; s >>= 1) {
        if (k < s) red[k] += red[k + s];
        __syncthreads();
    }
    const float nn = red[0];
    smoothed[k] = (ncs + 1e-5f) / (nn + 1024.f * 1e-5f) * nn;
    out[OFF_NCS + (size_t)k] = ncs;
    if (k == 0) out[OFF_LOSS] = 0.25f * lossAcc[0] / 8388608.f;
}

__global__ __launch_bounds__(256) void finalize2_kernel(
        const float* __restrict__ eavg, float* __restrict__ out,
        const float* __restrict__ esum_p, const float* __restrict__ smoothed,
        int P) {
    const int e = blockIdx.x * 256 + threadIdx.x;
    const int k = e >> 6;
    float s = 0.f;
    for (int p = 0; p < P; ++p) s += esum_p[(size_t)p * 65536 + e];
    const float ea = fmaf(0.01f, s, 0.99f * eavg[e]);
    out[OFF_EAVG + (size_t)e] = ea;
    out[OFF_EMB  + (size_t)e] = ea / smoothed[k];
}

extern "C" void kernel_launch(void* const* d_in, const int* in_sizes, int n_in,
                              void* d_out, int out_size, void* d_ws, size_t ws_size,
                              hipStream_t stream) {
    const float* z    = (const float*)d_in[0];
    const float* emb  = (const float*)d_in[1];
    const float* cs   = (const float*)d_in[2];
    const float* eavg = (const float*)d_in[3];
    float* out = (float*)d_out;

    int P = 1;
    for (int p = 16; p >= 1; p >>= 1)
        if (ws_size >= (size_t)p * 266240 + 266496) { P = p; break; }

    char* ws = (char*)d_ws;
    float*        esum_p = (float*)ws;
    unsigned int* cnt_p  = (unsigned int*)(ws + (size_t)P * 262144);
    float*        lossA  = (float*)(ws + (size_t)P * 266240);
    float*        smooth = (float*)(ws + (size_t)P * 266240 + 256);
    float*        embT   = (float*)(ws + (size_t)P * 266240 + 256 + 4096);
    unsigned short* wh = (unsigned short*)((char*)d_out + SCR_B0);
    unsigned short* wl = (unsigned short*)((char*)d_out + SCR_WLO);
    float*          w2 = (float*)((char*)d_out + SCR_W2O);

    (void)hipMemsetAsync(ws, 0, (size_t)P * 266240 + 256, stream);
    prep_kernel<<<16, 256, 0, stream>>>(emb, wh, wl, w2, embT);
    assign_kernel<<<NROWS / 256, 512, 0, stream>>>(
        z, emb, out, wh, wl, w2, embT, esum_p, cnt_p, lossA, P - 1);
    finalize1_kernel<<<1, 1024, 0, stream>>>(cs, out, cnt_p, lossA, smooth, P);
    finalize2_kernel<<<256, 256, 0, stream>>>(eavg, out, esum_p, smooth, P);
}